// Round 5
// baseline (26.758 us; speedup 1.0000x reference)
//
#include <hip/hip_runtime.h>
#include <hip/hip_bf16.h>
#include <cstdint>

// VQ-VAE vector quantize: N=65536 vectors, D=64, K=512 codes.
// d_in[0]: inputs fp32 [65536,64], d_in[1]: embeddings fp32 [512,64]
// d_out: [0]=loss, [1..4194304]=latent (gathered fp32 embeddings)

typedef __attribute__((ext_vector_type(8))) short bf16x8;
typedef __attribute__((ext_vector_type(4))) float f32x4;

__device__ __forceinline__ short f2bf(float f) {
    uint32_t u = __builtin_bit_cast(uint32_t, f);
    u += 0x7FFFu + ((u >> 16) & 1u);   // round-to-nearest-even
    return (short)(u >> 16);
}

// ws layout (bytes):
//  [0, 65536)     : B fragments bf16(-e), [ct(32)][ks(2)][lane(64)] x 16B
//  [65536, 67584) : ee_t[512] fp32 = 0.5*||e_k||^2, TRANSPOSED [cb(16)][ct(32)]
//  [67584, 69632) : partials[512] fp32
#define WS_EE   65536
#define WS_PART 67584

// ---------------- Kernel 1: setup (4 blocks x 256) ----------------
__global__ __launch_bounds__(256)
void vq_setup(const float* __restrict__ emb, char* __restrict__ ws) {
    const int tid = threadIdx.x, bid = blockIdx.x;
    bf16x8* bfrag = (bf16x8*)ws;
    float* eet = (float*)(ws + WS_EE);
    #pragma unroll
    for (int k = 0; k < 4; ++k) {
        const int s = bid * 1024 + k * 256 + tid;
        const int ct = s >> 7, ks = (s >> 6) & 1, ln = s & 63;
        const int code = (ct << 4) | (ln & 15);
        const int d0 = ks * 32 + ((ln >> 4) << 3);
        const float* src = emb + code * 64 + d0;
        float4 v0 = *(const float4*)src;
        float4 v1 = *(const float4*)(src + 4);
        bf16x8 b;
        b[0] = f2bf(-v0.x); b[1] = f2bf(-v0.y); b[2] = f2bf(-v0.z); b[3] = f2bf(-v0.w);
        b[4] = f2bf(-v1.x); b[5] = f2bf(-v1.y); b[6] = f2bf(-v1.z); b[7] = f2bf(-v1.w);
        bfrag[s] = b;
    }
    if (tid < 128) {
        const int c = bid * 128 + tid;           // code id
        const float4* e4 = (const float4*)(emb + c * 64);
        float s = 0.f;
        #pragma unroll
        for (int q = 0; q < 16; ++q) {
            float4 v = e4[q];
            s = fmaf(v.x, v.x, fmaf(v.y, v.y, fmaf(v.z, v.z, fmaf(v.w, v.w, s))));
        }
        eet[(c & 15) * 32 + (c >> 4)] = 0.5f * s;   // transposed, pre-halved
    }
}

// ---------------- Kernel 2: fused main (512 blocks x 256) ----------------
// Wave owns 32 rows (2 M-tiles). Codebook in 4 double-buffered 16 KB passes.
// Loss comes from the winning packed distance (no x re-read in epilogue).
__global__ __launch_bounds__(256)
void vq_main(const float* __restrict__ flat, const float* __restrict__ emb,
             char* __restrict__ ws, float* __restrict__ out) {
    __shared__ bf16x8 lbuf[2][1024];   // 2 x 16 KB
    __shared__ float red[4];

    const int tid = threadIdx.x, bid = blockIdx.x;
    const int lane = tid & 63, wid = tid >> 6;
    const int cb = lane & 15;
    const int rb = bid * 128 + wid * 32;   // wave's first row

    // ---- A loads: 2 M-tiles x 2 k-steps x 2 float4 ----
    float4 ar[2][2][2];
    #pragma unroll
    for (int mt = 0; mt < 2; ++mt)
        #pragma unroll
        for (int ks = 0; ks < 2; ++ks) {
            const int row = rb + mt * 16 + cb;
            const float* src = flat + (long)row * 64 + ks * 32 + ((lane >> 4) << 3);
            ar[mt][ks][0] = *(const float4*)src;
            ar[mt][ks][1] = *(const float4*)(src + 4);
        }

    // ---- issue stage of pass 0 into lbuf[0] (global_load_lds, linear) ----
    const char* wsg = (const char*)ws;
    {
        char* dst = (char*)&lbuf[0][0];
        #pragma unroll
        for (int k = 0; k < 4; ++k) {
            const int off = (k * 256 + tid) * 16;
            __builtin_amdgcn_global_load_lds(
                (const __attribute__((address_space(1))) void*)(wsg + off),
                (__attribute__((address_space(3))) void*)(dst + off), 16, 0, 0);
        }
    }

    // ---- preload 0.5*||e||^2 for this lane's 32 column-classes (32 VGPRs) ----
    float hv[32];
    {
        const float4* ee4 = (const float4*)(wsg + WS_EE + cb * 128);
        #pragma unroll
        for (int q = 0; q < 8; ++q) {
            float4 v = ee4[q];
            hv[q * 4 + 0] = v.x; hv[q * 4 + 1] = v.y;
            hv[q * 4 + 2] = v.z; hv[q * 4 + 3] = v.w;
        }
    }

    // ---- fp32 ||x||^2 partial (this lane's 32 loaded values) ----
    float xx = 0.f;
    #pragma unroll
    for (int mt = 0; mt < 2; ++mt)
        #pragma unroll
        for (int ks = 0; ks < 2; ++ks)
            #pragma unroll
            for (int u = 0; u < 2; ++u) {
                float4 v = ar[mt][ks][u];
                xx = fmaf(v.x, v.x, fmaf(v.y, v.y, fmaf(v.z, v.z, fmaf(v.w, v.w, xx))));
            }

    // ---- convert A to bf16 ----
    bf16x8 a[2][2];
    #pragma unroll
    for (int mt = 0; mt < 2; ++mt)
        #pragma unroll
        for (int ks = 0; ks < 2; ++ks) {
            float4 v0 = ar[mt][ks][0], v1 = ar[mt][ks][1];
            bf16x8 f;
            f[0] = f2bf(v0.x); f[1] = f2bf(v0.y); f[2] = f2bf(v0.z); f[3] = f2bf(v0.w);
            f[4] = f2bf(v1.x); f[5] = f2bf(v1.y); f[6] = f2bf(v1.z); f[7] = f2bf(v1.w);
            a[mt][ks] = f;
        }

    __syncthreads();   // pass-0 staging complete (vmcnt(0) at barrier)

    // ---- main loop: 4 passes x 8 col-tiles, double-buffered ----
    float pm[8];
    #pragma unroll
    for (int i = 0; i < 8; ++i) pm[i] = __builtin_bit_cast(float, 0x7F800000u);

    #pragma unroll
    for (int p = 0; p < 4; ++p) {
        if (p < 3) {   // issue next pass while computing this one
            char* dst = (char*)&lbuf[(p + 1) & 1][0];
            const int gbase = (p + 1) * 16384;
            #pragma unroll
            for (int k = 0; k < 4; ++k) {
                const int off = (k * 256 + tid) * 16;
                __builtin_amdgcn_global_load_lds(
                    (const __attribute__((address_space(1))) void*)(wsg + gbase + off),
                    (__attribute__((address_space(3))) void*)(dst + off), 16, 0, 0);
            }
        }
        const bf16x8* cur = &lbuf[p & 1][0];
        #pragma unroll
        for (int ctl = 0; ctl < 8; ++ctl) {
            bf16x8 b0 = cur[ctl * 128 + lane];
            bf16x8 b1 = cur[ctl * 128 + 64 + lane];
            const int ct = p * 8 + ctl;
            const int colv = (ct << 4) | cb;
            const float h = hv[ct];
            f32x4 acc0 = {h, h, h, h};   // 0.5||e||^2 - x.e  (B = -e)
            acc0 = __builtin_amdgcn_mfma_f32_16x16x32_bf16(a[0][0], b0, acc0, 0, 0, 0);
            acc0 = __builtin_amdgcn_mfma_f32_16x16x32_bf16(a[0][1], b1, acc0, 0, 0, 0);
            f32x4 acc1 = {h, h, h, h};
            acc1 = __builtin_amdgcn_mfma_f32_16x16x32_bf16(a[1][0], b0, acc1, 0, 0, 0);
            acc1 = __builtin_amdgcn_mfma_f32_16x16x32_bf16(a[1][1], b1, acc1, 0, 0, 0);
            #pragma unroll
            for (int j = 0; j < 4; ++j) {
                uint32_t d0 = (__builtin_bit_cast(uint32_t, acc0[j]) & 0xFFFFFE00u) | (uint32_t)colv;
                pm[j] = fminf(pm[j], __builtin_bit_cast(float, d0));
                uint32_t d1 = (__builtin_bit_cast(uint32_t, acc1[j]) & 0xFFFFFE00u) | (uint32_t)colv;
                pm[4 + j] = fminf(pm[4 + j], __builtin_bit_cast(float, d1));
            }
        }
        if (p < 3) __syncthreads();   // next pass staged; prev buffer reads drained
    }

    // ---- butterfly min over the 16 column-class lanes ----
    #pragma unroll
    for (int m = 1; m < 16; m <<= 1) {
        #pragma unroll
        for (int i = 0; i < 8; ++i)
            pm[i] = fminf(pm[i], __shfl_xor(pm[i], m, 64));
    }

    // ---- loss partial: sum_rows ( ||x||^2 + 2 * unpack(pm_min) ) ----
    float t = xx;
    if (cb == 0) {
        #pragma unroll
        for (int j = 0; j < 8; ++j) {
            float v = __builtin_bit_cast(float, __builtin_bit_cast(uint32_t, pm[j]) & 0xFFFFFE00u);
            t = fmaf(2.f, v, t);
        }
    }
    #pragma unroll
    for (int m = 32; m; m >>= 1) t += __shfl_down(t, m, 64);
    if (lane == 0) red[wid] = t;

    // ---- broadcast winning code of each of the wave's 32 rows ----
    int idxr[32];
    #pragma unroll
    for (int r = 0; r < 32; ++r) {
        const int mt = r >> 4, g = (r >> 2) & 3, j = r & 3;
        float v = __shfl(pm[mt * 4 + j], g << 4, 64);
        idxr[r] = (int)(__builtin_bit_cast(uint32_t, v) & 0x1FFu);
    }

    // ---- epilogue: gather + coalesced latent store (no x re-read) ----
    float* ob = out + 1 + (long)rb * 64;
    #pragma unroll 8
    for (int it = 0; it < 32; ++it) {
        float ev = emb[idxr[it] * 64 + lane];
        ob[it * 64 + lane] = ev;
    }

    __syncthreads();
    if (tid == 0) {
        float* part = (float*)(ws + WS_PART);
        part[bid] = red[0] + red[1] + red[2] + red[3];
    }
}

// ---------------- Kernel 3: deterministic final reduce (1 wave) ----------------
__global__ __launch_bounds__(64)
void vq_loss(const float* __restrict__ partials, float* __restrict__ out) {
    const int tid = threadIdx.x;
    float acc = 0.f;
    #pragma unroll
    for (int i = 0; i < 8; ++i) acc += partials[tid + i * 64];
    #pragma unroll
    for (int m = 32; m; m >>= 1) acc += __shfl_down(acc, m, 64);
    // loss = 0.25*e_loss + q_loss = 1.25 * mse (forward)
    if (tid == 0) out[0] = 1.25f * acc / 4194304.0f;
}

extern "C" void kernel_launch(void* const* d_in, const int* in_sizes, int n_in,
                              void* d_out, int out_size, void* d_ws, size_t ws_size,
                              hipStream_t stream) {
    const float* flat = (const float*)d_in[0];   // [65536,64]
    const float* emb  = (const float*)d_in[1];   // [512,64]
    float* out = (float*)d_out;
    char* ws = (char*)d_ws;

    vq_setup<<<4, 256, 0, stream>>>(emb, ws);
    vq_main<<<512, 256, 0, stream>>>(flat, emb, ws, out);
    vq_loss<<<1, 64, 0, stream>>>((const float*)(ws + WS_PART), out);
}